// Round 3
// baseline (624.384 us; speedup 1.0000x reference)
//
#include <hip/hip_runtime.h>

#define HEADS 6
#define N_TOK 144
#define DIM   192
#define NW    64
#define NB    15
#define NBW   (NB * NW)          // 960
#define CHUNK 480                // bw per chunk (2 chunks)

typedef __attribute__((ext_vector_type(8))) short bf16x8;
typedef __attribute__((ext_vector_type(4))) float f32x4;

#define MFMA(a, b, c) __builtin_amdgcn_mfma_f32_16x16x32_bf16(a, b, c, 0, 0, 0)

static __device__ __forceinline__ short f2bf(float f) {
    union { float f; unsigned u; } v; v.f = f;
    unsigned r = v.u + 0x7FFFu + ((v.u >> 16) & 1u);   // RNE
    return (short)(r >> 16);
}
static __device__ __forceinline__ float bf2f(short s) {
    union { unsigned u; float f; } v;
    v.u = ((unsigned)(unsigned short)s) << 16;
    return v.f;
}

// ---------------------------------------------------------------------------
// K0a: bias gather -> bf16, layout [(w*6+h)][i*144+j].
// ---------------------------------------------------------------------------
__global__ __launch_bounds__(256)
void bias_k(const float* __restrict__ table, const int* __restrict__ pos_index,
            short* __restrict__ bias_bf) {
    const int t = blockIdx.x;                      // w*6+h, 0..383
    for (int e = threadIdx.x; e < N_TOK * N_TOK; e += 256) {
        int idx = pos_index[e];
        bias_bf[(long)t * (N_TOK * N_TOK) + e] = f2bf(table[(long)idx * 384 + t]);
    }
}

// K0b: f32 -> bf16 copy
__global__ __launch_bounds__(256)
void cvt_k(const float* __restrict__ w, short* __restrict__ o, int n) {
    int i = blockIdx.x * 256 + threadIdx.x;
    if (i < n) o[i] = f2bf(w[i]);
}

// ---------------------------------------------------------------------------
// K1: QKV projection GEMM. Block = bw; x staged to LDS bf16 ONCE (pad 200),
// all 3 sels (N=576) computed here. B-frags from L2-resident bf16 qkv_w.
// 9 waves = 3 M-groups x 3 sels; wave = 3 M-tiles x 12 N-tiles, K = 6x32.
// Output bf16 qkv_ws[((bwL*6+h)*3+sel)][row][e], q pre-scaled.
// ---------------------------------------------------------------------------
__global__ __launch_bounds__(576)
void qkvg_k(const float* __restrict__ x, const short* __restrict__ qkvw_bf,
            const float* __restrict__ qkv_b, short* __restrict__ qkv_out,
            int bw0) {
    __shared__ short xlds[N_TOK * 200];
    const int bwL = blockIdx.x;
    const int bwG = bw0 + bwL;
    const int tid = threadIdx.x;
    const float* xb = x + (long)bwG * N_TOK * DIM;

    // stage x as bf16 (float4 loads, short4 LDS writes)
    for (int u = tid * 4; u < N_TOK * DIM; u += 576 * 4) {
        int r = u / DIM, c = u - r * DIM;
        float4 f = *(const float4*)&xb[u];
        short4 s = { f2bf(f.x), f2bf(f.y), f2bf(f.z), f2bf(f.w) };
        *(short4*)&xlds[r * 200 + c] = s;
    }
    __syncthreads();

    const int wid = tid >> 6, lane = tid & 63, lq = lane & 15, lg = lane >> 4;
    const int mg = wid / 3, sel = wid % 3;

    f32x4 acc[3][12] = {};
    for (int ks = 0; ks < 6; ++ks) {
        const int k0 = ks * 32 + 8 * lg;
        bf16x8 av[3];
        #pragma unroll
        for (int mt = 0; mt < 3; ++mt)
            av[mt] = *(const bf16x8*)&xlds[(mg * 48 + mt * 16 + lq) * 200 + k0];
        #pragma unroll
        for (int nt = 0; nt < 12; ++nt) {
            bf16x8 bv = *(const bf16x8*)&qkvw_bf[(sel * 192 + nt * 16 + lq) * 192 + k0];
            #pragma unroll
            for (int mt = 0; mt < 3; ++mt)
                acc[mt][nt] = MFMA(av[mt], bv, acc[mt][nt]);
        }
    }

    const float scale = 0.17677669529663687f;   // 32^-0.5
    #pragma unroll
    for (int nt = 0; nt < 12; ++nt) {
        const int cd = nt * 16 + lq;            // channel within sel, 0..191
        const float bb = qkv_b[sel * 192 + cd];
        const int h = cd >> 5, e = cd & 31;
        short* ob = qkv_out + ((long)(bwL * 6 + h) * 3 + sel) * 4608 + e;
        #pragma unroll
        for (int mt = 0; mt < 3; ++mt)
            #pragma unroll
            for (int i = 0; i < 4; ++i) {
                int row = mg * 48 + mt * 16 + 4 * lg + i;
                float v = acc[mt][nt][i] + bb;
                if (sel == 0) v *= scale;
                ob[row * 32] = f2bf(v);
            }
    }
}

// ---------------------------------------------------------------------------
// K2: attention. Block = bw, loops over all 6 heads (mask read once per bw,
// L2-hit for heads 1..5). 9 waves, wave = 16 query rows.
// ---------------------------------------------------------------------------
__global__ __launch_bounds__(576)
void attn_k(const short* __restrict__ qkv, const short* __restrict__ bias_bf,
            const float* __restrict__ mask, short* __restrict__ tmp, int bw0) {
    __shared__ short shmem[9 * 16 * 152 + 32 * 152 + 128];
    short* plds = shmem;                 // 9 waves x [16][152]
    short* vlds = shmem + 9 * 16 * 152;  // [32][152] (+128 slack)

    const int bwL = blockIdx.x;
    const int bwG = bw0 + bwL;
    const int tid = threadIdx.x;
    const int lane = tid & 63, lq = lane & 15, lg = lane >> 4;
    const int wid = tid >> 6;
    const int m0 = wid * 16;
    const int w = bwG & 63;
    const float* mp = mask + (long)bwG * (N_TOK * N_TOK);
    short* pw = plds + wid * 16 * 152;
    short* tb = tmp + (long)bwL * N_TOK * DIM;

    #pragma unroll 1
    for (int h = 0; h < HEADS; ++h) {
        const short* qb = qkv + ((long)(bwL * 6 + h) * 3) * 4608;
        const short* kb = qb + 4608;
        const short* vb = qb + 9216;

        __syncthreads();   // previous head's PV done with vlds
        {
            int j = tid >> 2, e0 = (tid & 3) * 8;
            bf16x8 vv = *(const bf16x8*)&vb[j * 32 + e0];
            #pragma unroll
            for (int u = 0; u < 8; ++u) vlds[(e0 + u) * 152 + j] = vv[u];
        }
        __syncthreads();

        // ---- QK^T ----
        const f32x4 zf = {};
        bf16x8 aq = *(const bf16x8*)&qb[(m0 + lq) * 32 + 8 * lg];
        f32x4 lgt[9];
        #pragma unroll
        for (int nt = 0; nt < 9; ++nt) {
            bf16x8 bk = *(const bf16x8*)&kb[(nt * 16 + lq) * 32 + 8 * lg];
            lgt[nt] = MFMA(aq, bk, zf);
        }

        // ---- + bias + mask ----
        const short* bp = bias_bf + (long)(w * 6 + h) * (N_TOK * N_TOK);
        #pragma unroll
        for (int nt = 0; nt < 9; ++nt)
            #pragma unroll
            for (int i = 0; i < 4; ++i) {
                int r = m0 + 4 * lg + i, c = nt * 16 + lq;
                lgt[nt][i] += bf2f(bp[r * N_TOK + c]) + mp[r * N_TOK + c];
            }

        // ---- softmax (rows 4*lg+i per lane) ----
        float inv_s[4];
        #pragma unroll
        for (int i = 0; i < 4; ++i) {
            float m = lgt[0][i];
            #pragma unroll
            for (int nt = 1; nt < 9; ++nt) m = fmaxf(m, lgt[nt][i]);
            m = fmaxf(m, __shfl_xor(m, 1));
            m = fmaxf(m, __shfl_xor(m, 2));
            m = fmaxf(m, __shfl_xor(m, 4));
            m = fmaxf(m, __shfl_xor(m, 8));
            float s = 0.f;
            #pragma unroll
            for (int nt = 0; nt < 9; ++nt) {
                float p = __expf(lgt[nt][i] - m);
                lgt[nt][i] = p;
                s += p;
            }
            s += __shfl_xor(s, 1);
            s += __shfl_xor(s, 2);
            s += __shfl_xor(s, 4);
            s += __shfl_xor(s, 8);
            inv_s[i] = 1.f / s;
        }

        // ---- P -> LDS (per-wave region; same-wave consume) ----
        #pragma unroll
        for (int nt = 0; nt < 9; ++nt)
            #pragma unroll
            for (int i = 0; i < 4; ++i)
                pw[(4 * lg + i) * 152 + nt * 16 + lq] = f2bf(lgt[nt][i]);

        // ---- PV ----
        f32x4 o[2] = {};
        const bf16x8 zb = {};
        #pragma unroll
        for (int ks = 0; ks < 5; ++ks) {
            bf16x8 ap = *(const bf16x8*)&pw[lq * 152 + ks * 32 + 8 * lg];
            #pragma unroll
            for (int nt = 0; nt < 2; ++nt) {
                bf16x8 bv = *(const bf16x8*)&vlds[(nt * 16 + lq) * 152 + ks * 32 + 8 * lg];
                if (ks == 4 && lg >= 2) { ap = zb; bv = zb; }   // keys 144..159
                o[nt] = MFMA(ap, bv, o[nt]);
            }
        }

        // ---- normalize, write tmp bf16 [bwL][row][h*32+e] ----
        #pragma unroll
        for (int nt = 0; nt < 2; ++nt)
            #pragma unroll
            for (int i = 0; i < 4; ++i) {
                int row = m0 + 4 * lg + i;
                tb[row * DIM + h * 32 + nt * 16 + lq] = f2bf(o[nt][i] * inv_s[i]);
            }
    }
}

// ---------------------------------------------------------------------------
// K3: output projection. Block = (bwL, m-third), 3 waves, wave = 16 rows.
// A from tmp bf16 (16B loads), B from L2-resident bf16 proj_w. No LDS.
// ---------------------------------------------------------------------------
__global__ __launch_bounds__(192)
void proj_k(const short* __restrict__ tmp, const short* __restrict__ pwt,
            const float* __restrict__ proj_b, float* __restrict__ out, int bw0) {
    const int bid = blockIdx.x;
    const int mthird = bid % 3;
    const int bwL = bid / 3;
    const int bwG = bw0 + bwL;
    const int tid = threadIdx.x;
    const int wid = tid >> 6, lane = tid & 63, lq = lane & 15, lg = lane >> 4;
    const int m0 = (mthird * 3 + wid) * 16;
    const short* tb = tmp + (long)bwL * N_TOK * DIM;

    f32x4 acc[12] = {};
    for (int ks = 0; ks < 6; ++ks) {
        const int k0 = ks * 32 + 8 * lg;
        bf16x8 a = *(const bf16x8*)&tb[(m0 + lq) * DIM + k0];
        #pragma unroll
        for (int nt = 0; nt < 12; ++nt) {
            bf16x8 b = *(const bf16x8*)&pwt[(nt * 16 + lq) * DIM + k0];
            acc[nt] = MFMA(a, b, acc[nt]);
        }
    }
    float* ob = out + (long)bwG * N_TOK * DIM;
    #pragma unroll
    for (int nt = 0; nt < 12; ++nt) {
        float pb = proj_b[nt * 16 + lq];
        #pragma unroll
        for (int i = 0; i < 4; ++i)
            ob[(m0 + 4 * lg + i) * DIM + nt * 16 + lq] = acc[nt][i] + pb;
    }
}

// ---------------------------------------------------------------------------
extern "C" void kernel_launch(void* const* d_in, const int* in_sizes, int n_in,
                              void* d_out, int out_size, void* d_ws, size_t ws_size,
                              hipStream_t stream) {
    const float* x        = (const float*)d_in[0];
    const float* mask     = (const float*)d_in[1];
    const float* qkv_w    = (const float*)d_in[2];
    const float* qkv_b    = (const float*)d_in[3];
    const float* table    = (const float*)d_in[4];
    const float* proj_w   = (const float*)d_in[5];
    const float* proj_b   = (const float*)d_in[6];
    const int*   pos_index= (const int*)d_in[7];
    float* out = (float*)d_out;

    // ws layout (bf16 shorts), total ~122.7 MB:
    //  bias_bf  [384][144*144]            15.93 MB
    //  projw_bf [192*192]                  0.07 MB
    //  qkvw_bf  [576*192]                  0.22 MB
    //  qkv_ws   [CHUNK*6 x 3 x 144 x 32]  79.63 MB (reused per chunk)
    //  tmp_ws   [CHUNK x 144 x 192]       26.54 MB (reused per chunk)
    short* bias_bf  = (short*)d_ws;
    short* projw_bf = bias_bf + (size_t)384 * N_TOK * N_TOK;
    short* qkvw_bf  = projw_bf + 36864;
    short* qkv_ws   = qkvw_bf + 110592;
    short* tmp_ws   = qkv_ws + (size_t)CHUNK * 6 * 3 * 4608;

    bias_k<<<384, 256, 0, stream>>>(table, pos_index, bias_bf);
    cvt_k<<<144, 256, 0, stream>>>(proj_w, projw_bf, DIM * DIM);
    cvt_k<<<432, 256, 0, stream>>>(qkv_w, qkvw_bf, 3 * DIM * DIM);

    for (int c = 0; c < 2; ++c) {
        const int bw0 = c * CHUNK;
        qkvg_k<<<CHUNK, 576, 0, stream>>>(x, qkvw_bf, qkv_b, qkv_ws, bw0);
        attn_k<<<CHUNK, 576, 0, stream>>>(qkv_ws, bias_bf, mask, tmp_ws, bw0);
        proj_k<<<CHUNK * 3, 192, 0, stream>>>(tmp_ws, projw_bf, proj_b, out, bw0);
    }
}

// Round 4
// 533.220 us; speedup vs baseline: 1.1710x; 1.1710x over previous
//
#include <hip/hip_runtime.h>

#define HEADS 6
#define N_TOK 144
#define DIM   192
#define NW    64
#define NB    15
#define NBW   (NB * NW)          // 960
#define CHUNK 480                // bw per chunk (2 chunks)

typedef __attribute__((ext_vector_type(8))) short bf16x8;
typedef __attribute__((ext_vector_type(4))) float f32x4;

#define MFMA(a, b, c) __builtin_amdgcn_mfma_f32_16x16x32_bf16(a, b, c, 0, 0, 0)

static __device__ __forceinline__ short f2bf(float f) {
    union { float f; unsigned u; } v; v.f = f;
    unsigned r = v.u + 0x7FFFu + ((v.u >> 16) & 1u);   // RNE
    return (short)(r >> 16);
}
static __device__ __forceinline__ float bf2f(short s) {
    union { unsigned u; float f; } v;
    v.u = ((unsigned)(unsigned short)s) << 16;
    return v.f;
}

// ---------------------------------------------------------------------------
// K0a: bias gather -> bf16, layout [(w*6+h)][i*144+j].
// ---------------------------------------------------------------------------
__global__ __launch_bounds__(256)
void bias_k(const float* __restrict__ table, const int* __restrict__ pos_index,
            short* __restrict__ bias_bf) {
    const int t = blockIdx.x;                      // w*6+h, 0..383
    for (int e = threadIdx.x; e < N_TOK * N_TOK; e += 256) {
        int idx = pos_index[e];
        bias_bf[(long)t * (N_TOK * N_TOK) + e] = f2bf(table[(long)idx * 384 + t]);
    }
}

// K0b: f32 -> bf16 scalar copy (weights)
__global__ __launch_bounds__(256)
void cvt_k(const float* __restrict__ w, short* __restrict__ o, int n) {
    int i = blockIdx.x * 256 + threadIdx.x;
    if (i < n) o[i] = f2bf(w[i]);
}

// K0c: f32 -> bf16 vectorized (x, per chunk)
__global__ __launch_bounds__(256)
void cvtx_k(const float* __restrict__ x, short* __restrict__ xb, int n4) {
    int i = blockIdx.x * 256 + threadIdx.x;
    if (i < n4) {
        float4 f = ((const float4*)x)[i];
        short4 s = { f2bf(f.x), f2bf(f.y), f2bf(f.z), f2bf(f.w) };
        ((short4*)xb)[i] = s;
    }
}

// ---------------------------------------------------------------------------
// K1: QKV GEMM. Block = (bwL, sel). W_sel in LDS (bf16x8 staged, stride 200).
// A-frags straight from chunk-local x_bf global. 9 waves = 3mg x 3ng,
// wave tile 48x64 (48 acc regs). Epilogue: acc -> LDS [144][200] -> coalesced
// bf16x8 stores to qkv_ws[((bwL*6+h)*3+sel)][row][32e]. q pre-scaled.
// ---------------------------------------------------------------------------
__global__ __launch_bounds__(576)
void qkvs_k(const short* __restrict__ xb, const short* __restrict__ qkvw_bf,
            const float* __restrict__ qkv_b, short* __restrict__ qkv_out) {
    __shared__ short wlds[192 * 200];   // W_sel [oc][k]; reused for out staging

    const int sel = blockIdx.x % 3;
    const int bwL = blockIdx.x / 3;
    const int tid = threadIdx.x;

    // stage W_sel (bf16x8 loads/stores, 8 iters)
    for (int u = tid * 8; u < 192 * 192; u += 576 * 8) {
        int r = u / 192, c = u - r * 192;
        *(bf16x8*)&wlds[r * 200 + c] = *(const bf16x8*)&qkvw_bf[sel * 36864 + u];
    }
    __syncthreads();

    const int wid = tid >> 6, lane = tid & 63, lq = lane & 15, lg = lane >> 4;
    const int mg = wid / 3, ng = wid % 3;
    const short* xrow = xb + (long)bwL * N_TOK * DIM;

    f32x4 acc[3][4] = {};
    for (int ks = 0; ks < 6; ++ks) {
        const int k0 = ks * 32 + 8 * lg;
        bf16x8 av[3], bv[4];
        #pragma unroll
        for (int mt = 0; mt < 3; ++mt)
            av[mt] = *(const bf16x8*)&xrow[(mg * 48 + mt * 16 + lq) * DIM + k0];
        #pragma unroll
        for (int nt = 0; nt < 4; ++nt)
            bv[nt] = *(const bf16x8*)&wlds[(ng * 64 + nt * 16 + lq) * 200 + k0];
        #pragma unroll
        for (int mt = 0; mt < 3; ++mt)
            #pragma unroll
            for (int nt = 0; nt < 4; ++nt)
                acc[mt][nt] = MFMA(av[mt], bv[nt], acc[mt][nt]);
    }
    __syncthreads();   // all waves done reading W -> reuse wlds

    // stage outputs into LDS [row][ch0..191] (stride 200)
    const float scale = 0.17677669529663687f;   // 32^-0.5
    #pragma unroll
    for (int nt = 0; nt < 4; ++nt) {
        const int cd = ng * 64 + nt * 16 + lq;          // 0..191
        const float bb = qkv_b[sel * 192 + cd];
        #pragma unroll
        for (int mt = 0; mt < 3; ++mt)
            #pragma unroll
            for (int i = 0; i < 4; ++i) {
                int row = mg * 48 + mt * 16 + 4 * lg + i;
                float v = acc[mt][nt][i] + bb;
                if (sel == 0) v *= scale;
                wlds[row * 200 + cd] = f2bf(v);
            }
    }
    __syncthreads();

    // coalesced copy out: 27648 elems, bf16x8, 6 iters
    short* ob = qkv_out + (long)bwL * 6 * 3 * 4608 + (long)sel * 4608;
    #pragma unroll
    for (int j = 0; j < 6; ++j) {
        int u = (j * 576 + tid) * 8;        // 0..27647
        int h = u / 4608, rem = u - h * 4608;
        int row = rem >> 5, e = rem & 31;
        *(bf16x8*)&ob[(long)h * 3 * 4608 + rem] =
            *(const bf16x8*)&wlds[row * 200 + h * 32 + e];
    }
}

// ---------------------------------------------------------------------------
// K2: fused attention + output projection. Block = bwL, 9 waves.
// Per head: v->LDS(transposed), QK^T (global frags), +bias+mask, reg softmax,
// P->LDS, PV, result -> outb LDS [144][200]. After 6 heads: proj GEMM from
// outb x L2-resident bf16 proj_w -> d_out fp32 (coalesced).
// ---------------------------------------------------------------------------
__global__ __launch_bounds__(576)
void attnproj_k(const short* __restrict__ qkv, const short* __restrict__ bias_bf,
                const float* __restrict__ mask, const short* __restrict__ pwt,
                const float* __restrict__ proj_b, float* __restrict__ out,
                int bw0) {
    __shared__ short pw_s[9 * 16 * 152];   // 43,776 B
    __shared__ short vlds[32 * 152];       //  9,728 B
    __shared__ short outb[N_TOK * 200];    // 57,600 B

    const int bwL = blockIdx.x;
    const int bwG = bw0 + bwL;
    const int tid = threadIdx.x;
    const int lane = tid & 63, lq = lane & 15, lg = lane >> 4;
    const int wid = tid >> 6;
    const int m0 = wid * 16;
    const int w = bwG & 63;
    const float* mp = mask + (long)bwG * (N_TOK * N_TOK);
    short* pw = pw_s + wid * 16 * 152;

    #pragma unroll 1
    for (int h = 0; h < HEADS; ++h) {
        const short* qb = qkv + ((long)(bwL * 6 + h) * 3) * 4608;
        const short* kb = qb + 4608;
        const short* vb = qb + 9216;

        __syncthreads();   // previous head done with vlds
        {
            int j = tid >> 2, e0 = (tid & 3) * 8;
            bf16x8 vv = *(const bf16x8*)&vb[j * 32 + e0];
            #pragma unroll
            for (int u = 0; u < 8; ++u) vlds[(e0 + u) * 152 + j] = vv[u];
        }
        __syncthreads();

        // ---- QK^T ----
        const f32x4 zf = {};
        bf16x8 aq = *(const bf16x8*)&qb[(m0 + lq) * 32 + 8 * lg];
        f32x4 lgt[9];
        #pragma unroll
        for (int nt = 0; nt < 9; ++nt) {
            bf16x8 bk = *(const bf16x8*)&kb[(nt * 16 + lq) * 32 + 8 * lg];
            lgt[nt] = MFMA(aq, bk, zf);
        }

        // ---- + bias + mask ----
        const short* bp = bias_bf + (long)(w * 6 + h) * (N_TOK * N_TOK);
        #pragma unroll
        for (int nt = 0; nt < 9; ++nt)
            #pragma unroll
            for (int i = 0; i < 4; ++i) {
                int r = m0 + 4 * lg + i, c = nt * 16 + lq;
                lgt[nt][i] += bf2f(bp[r * N_TOK + c]) + mp[r * N_TOK + c];
            }

        // ---- softmax (rows 4*lg+i per lane) ----
        float inv_s[4];
        #pragma unroll
        for (int i = 0; i < 4; ++i) {
            float m = lgt[0][i];
            #pragma unroll
            for (int nt = 1; nt < 9; ++nt) m = fmaxf(m, lgt[nt][i]);
            m = fmaxf(m, __shfl_xor(m, 1));
            m = fmaxf(m, __shfl_xor(m, 2));
            m = fmaxf(m, __shfl_xor(m, 4));
            m = fmaxf(m, __shfl_xor(m, 8));
            float s = 0.f;
            #pragma unroll
            for (int nt = 0; nt < 9; ++nt) {
                float p = __expf(lgt[nt][i] - m);
                lgt[nt][i] = p;
                s += p;
            }
            s += __shfl_xor(s, 1);
            s += __shfl_xor(s, 2);
            s += __shfl_xor(s, 4);
            s += __shfl_xor(s, 8);
            inv_s[i] = 1.f / s;
        }

        // ---- P -> LDS (per-wave region; same-wave consume) ----
        #pragma unroll
        for (int nt = 0; nt < 9; ++nt)
            #pragma unroll
            for (int i = 0; i < 4; ++i)
                pw[(4 * lg + i) * 152 + nt * 16 + lq] = f2bf(lgt[nt][i]);

        // ---- PV ----
        f32x4 o[2] = {};
        const bf16x8 zb = {};
        #pragma unroll
        for (int ks = 0; ks < 5; ++ks) {
            bf16x8 ap = *(const bf16x8*)&pw[lq * 152 + ks * 32 + 8 * lg];
            #pragma unroll
            for (int nt = 0; nt < 2; ++nt) {
                bf16x8 bv = *(const bf16x8*)&vlds[(nt * 16 + lq) * 152 + ks * 32 + 8 * lg];
                if (ks == 4 && lg >= 2) { ap = zb; bv = zb; }   // keys 144..159
                o[nt] = MFMA(ap, bv, o[nt]);
            }
        }

        // ---- normalize -> outb LDS [row][h*32+e] ----
        #pragma unroll
        for (int nt = 0; nt < 2; ++nt)
            #pragma unroll
            for (int i = 0; i < 4; ++i) {
                int row = m0 + 4 * lg + i;
                outb[row * 200 + h * 32 + nt * 16 + lq] = f2bf(o[nt][i] * inv_s[i]);
            }
    }
    __syncthreads();   // outb complete

    // ---- proj: [144,192] = outb @ pwt^T, wave = 16 rows x 192 cols ----
    f32x4 acc[12] = {};
    for (int ks = 0; ks < 6; ++ks) {
        const int k0 = ks * 32 + 8 * lg;
        bf16x8 a = *(const bf16x8*)&outb[(m0 + lq) * 200 + k0];
        #pragma unroll
        for (int nt = 0; nt < 12; ++nt) {
            bf16x8 b = *(const bf16x8*)&pwt[(nt * 16 + lq) * DIM + k0];
            acc[nt] = MFMA(a, b, acc[nt]);
        }
    }
    float* ob = out + (long)bwG * N_TOK * DIM;
    #pragma unroll
    for (int nt = 0; nt < 12; ++nt) {
        float pb = proj_b[nt * 16 + lq];
        #pragma unroll
        for (int i = 0; i < 4; ++i)
            ob[(m0 + 4 * lg + i) * DIM + nt * 16 + lq] = acc[nt][i] + pb;
    }
}

// ---------------------------------------------------------------------------
extern "C" void kernel_launch(void* const* d_in, const int* in_sizes, int n_in,
                              void* d_out, int out_size, void* d_ws, size_t ws_size,
                              hipStream_t stream) {
    const float* x        = (const float*)d_in[0];
    const float* mask     = (const float*)d_in[1];
    const float* qkv_w    = (const float*)d_in[2];
    const float* qkv_b    = (const float*)d_in[3];
    const float* table    = (const float*)d_in[4];
    const float* proj_w   = (const float*)d_in[5];
    const float* proj_b   = (const float*)d_in[6];
    const int*   pos_index= (const int*)d_in[7];
    float* out = (float*)d_out;

    // ws layout (bf16 shorts), total ~122.4 MB:
    //  bias_bf  [384][144*144]            15.93 MB
    //  projw_bf [192*192]                  0.07 MB
    //  qkvw_bf  [576*192]                  0.22 MB
    //  xbf_ws   [CHUNK x 144 x 192]       26.54 MB (per chunk)
    //  qkv_ws   [CHUNK*6 x 3 x 144 x 32]  79.63 MB (per chunk)
    short* bias_bf  = (short*)d_ws;
    short* projw_bf = bias_bf + (size_t)384 * N_TOK * N_TOK;
    short* qkvw_bf  = projw_bf + 36864;
    short* xbf_ws   = qkvw_bf + 110592;
    short* qkv_ws   = xbf_ws + (size_t)CHUNK * N_TOK * DIM;

    bias_k<<<384, 256, 0, stream>>>(table, pos_index, bias_bf);
    cvt_k<<<144, 256, 0, stream>>>(proj_w, projw_bf, DIM * DIM);
    cvt_k<<<432, 256, 0, stream>>>(qkv_w, qkvw_bf, 3 * DIM * DIM);

    const int n4 = CHUNK * N_TOK * DIM / 4;   // 3,317,760
    for (int c = 0; c < 2; ++c) {
        const int bw0 = c * CHUNK;
        cvtx_k<<<(n4 + 255) / 256, 256, 0, stream>>>(
            x + (long)bw0 * N_TOK * DIM, xbf_ws, n4);
        qkvs_k<<<CHUNK * 3, 576, 0, stream>>>(xbf_ws, qkvw_bf, qkv_b, qkv_ws);
        attnproj_k<<<CHUNK, 576, 0, stream>>>(qkv_ws, bias_bf, mask, projw_bf,
                                              proj_b, out, bw0);
    }
}